// Round 1
// baseline (440.267 us; speedup 1.0000x reference)
//
#include <hip/hip_runtime.h>

typedef unsigned short u16;
typedef __bf16 bf16x8 __attribute__((ext_vector_type(8)));
typedef float f32x4 __attribute__((ext_vector_type(4)));

#define DIN 2048
#define DOUT 8192
#define MROWS 8192            // B*S = 4*2048
#define NELEM_W (8192 * 2048) // 16777216

// workspace layout (bytes)
#define WS_PART 0                       // double[2048] partial |w| sums
#define WS_WFAC 16384                   // float: clamped mean|w|  (dequant factor for weights)
#define WS_ROWFAC 16640                 // float[8192]: per-row amax_c/127
#define WS_XQ 49408                     // u16[8192*2048] bf16 quantized activations (integers)
#define WS_WQ (49408 + 33554432)        // u16[8192*2048] bf16 ternary weights

// ---------------- weight abs-sum (stage 1): deterministic partials ----------
__global__ void k_wabs(const float* __restrict__ w, double* __restrict__ part) {
    const float4* w4 = (const float4*)w;
    const unsigned t = threadIdx.x, b = blockIdx.x;
    float s = 0.f;
    for (unsigned i = b * 256u + t; i < (NELEM_W / 4); i += 2048u * 256u) {
        float4 v = w4[i];
        s += fabsf(v.x) + fabsf(v.y) + fabsf(v.z) + fabsf(v.w);
    }
    double d = (double)s;
    #pragma unroll
    for (int o = 32; o; o >>= 1) d += __shfl_down(d, o);
    __shared__ double red[4];
    if ((t & 63u) == 0u) red[t >> 6] = d;
    __syncthreads();
    if (t == 0) part[b] = red[0] + red[1] + red[2] + red[3];
}

// ---------------- weight abs-mean (stage 2): single block -------------------
__global__ void k_wfin(const double* __restrict__ part, float* __restrict__ wfac) {
    const int t = threadIdx.x; // 256 threads, 2048 partials
    double s = 0.0;
    #pragma unroll
    for (int j = 0; j < 8; ++j) s += part[t + j * 256];
    #pragma unroll
    for (int o = 32; o; o >>= 1) s += __shfl_down(s, o);
    __shared__ double red[4];
    if ((t & 63) == 0) red[t >> 6] = s;
    __syncthreads();
    if (t == 0) {
        double mean = (red[0] + red[1] + red[2] + red[3]) * (1.0 / (double)NELEM_W);
        *wfac = fmaxf((float)mean, 1e-5f);
    }
}

// ---------------- ternary weight quant: w -> bf16 {-1,0,1} ------------------
__global__ void k_wquant(const float* __restrict__ w, const float* __restrict__ wfac,
                         u16* __restrict__ wq) {
    const float scale = 1.0f / *wfac;
    const float4* w4 = (const float4*)w;
    uint2* wo = (uint2*)wq;
    for (unsigned i = blockIdx.x * 256u + threadIdx.x; i < (NELEM_W / 4); i += 2048u * 256u) {
        float4 v = w4[i];
        unsigned q0 = __float_as_uint(fminf(fmaxf(rintf(v.x * scale), -1.f), 1.f)) >> 16;
        unsigned q1 = __float_as_uint(fminf(fmaxf(rintf(v.y * scale), -1.f), 1.f)) >> 16;
        unsigned q2 = __float_as_uint(fminf(fmaxf(rintf(v.z * scale), -1.f), 1.f)) >> 16;
        unsigned q3 = __float_as_uint(fminf(fmaxf(rintf(v.w * scale), -1.f), 1.f)) >> 16;
        uint2 u;
        u.x = q0 | (q1 << 16);
        u.y = q2 | (q3 << 16);
        wo[i] = u;
    }
}

// ---------------- fused RMS-norm + per-row int8 quant -> bf16 ints ----------
__global__ void k_act(const float* __restrict__ x, u16* __restrict__ xq,
                      float* __restrict__ rowfac) {
    const int row = blockIdx.x, t = threadIdx.x; // 8192 rows, 256 threads
    const float4* xr = (const float4*)(x + (size_t)row * DIN);
    float4 v0 = xr[t], v1 = xr[t + 256];
    float ss = v0.x * v0.x + v0.y * v0.y + v0.z * v0.z + v0.w * v0.w
             + v1.x * v1.x + v1.y * v1.y + v1.z * v1.z + v1.w * v1.w;
    __shared__ float red[4];
    #pragma unroll
    for (int o = 32; o; o >>= 1) ss += __shfl_down(ss, o);
    if ((t & 63) == 0) red[t >> 6] = ss;
    __syncthreads();
    ss = red[0] + red[1] + red[2] + red[3];
    const float r = 1.0f / sqrtf(ss * (1.0f / DIN) + 1.1920929e-7f); // finfo(f32).eps
    float xn[8] = {v0.x * r, v0.y * r, v0.z * r, v0.w * r,
                   v1.x * r, v1.y * r, v1.z * r, v1.w * r};
    float am = 0.f;
    #pragma unroll
    for (int j = 0; j < 8; ++j) am = fmaxf(am, fabsf(xn[j]));
    __syncthreads(); // red reuse
    #pragma unroll
    for (int o = 32; o; o >>= 1) am = fmaxf(am, __shfl_down(am, o));
    if ((t & 63) == 0) red[t >> 6] = am;
    __syncthreads();
    am = fmaxf(fmaxf(red[0], red[1]), fmaxf(red[2], red[3]));
    const float amc = fmaxf(am, 1e-5f);
    const float s = 127.0f / amc;
    unsigned q[8];
    #pragma unroll
    for (int j = 0; j < 8; ++j) {
        float qv = fminf(fmaxf(rintf(xn[j] * s), -128.f), 127.f);
        q[j] = __float_as_uint(qv) >> 16;
    }
    uint2* xo = (uint2*)(xq + (size_t)row * DIN);
    uint2 u0, u1;
    u0.x = q[0] | (q[1] << 16); u0.y = q[2] | (q[3] << 16);
    u1.x = q[4] | (q[5] << 16); u1.y = q[6] | (q[7] << 16);
    xo[t] = u0;
    xo[t + 256] = u1;
    if (t == 0) rowfac[row] = amc * (1.0f / 127.0f);
}

// ---------------- GEMM: C[m,n] = (sum_k Xq[m,k]*Wq[n,k]) * rowfac[m] * wfac --
// m97 structure: 128x128 tile, BK=64, 4 waves (2x2), global_load_lds staging,
// 16x16x32 bf16 MFMA. Both operands are [rows][K] row-major (B^T-input GEMM).
__launch_bounds__(256)
__global__ void k_gemm(const u16* __restrict__ A, const u16* __restrict__ Bw,
                       const float* __restrict__ rowfac, const float* __restrict__ wfac,
                       float* __restrict__ out) {
    __shared__ __attribute__((aligned(16))) u16 sA[128 * 64];
    __shared__ __attribute__((aligned(16))) u16 sB[128 * 64];
    const int t = threadIdx.x;
    const int l = t & 63, w = t >> 6;
    const int bn = blockIdx.x, bm = blockIdx.y;
    const int wr = (w >> 1) * 64, wc = (w & 1) * 64;
    const int lr = l & 15, kq = (l >> 4) * 8;
    const int srow = l >> 3;        // row within 8-row staging chunk
    const int scol = (l & 7) * 8;   // element offset within BK

    const u16* Ab = A + (size_t)(bm * 128) * DIN;
    const u16* Bb = Bw + (size_t)(bn * 128) * DIN;

    f32x4 acc[4][4] = {};

    for (int kt = 0; kt < DIN; kt += 64) {
        __syncthreads(); // protect LDS while previous tile still computing
        #pragma unroll
        for (int i = 0; i < 4; ++i) {
            const int chunk = w * 4 + i;            // wave-uniform
            const int row = chunk * 8 + srow;
            __builtin_amdgcn_global_load_lds(
                (const __attribute__((address_space(1))) void*)(Ab + (size_t)row * DIN + kt + scol),
                (__attribute__((address_space(3))) void*)(&sA[chunk * 512]), 16, 0, 0);
            __builtin_amdgcn_global_load_lds(
                (const __attribute__((address_space(1))) void*)(Bb + (size_t)row * DIN + kt + scol),
                (__attribute__((address_space(3))) void*)(&sB[chunk * 512]), 16, 0, 0);
        }
        __syncthreads(); // compiler drains vmcnt before barrier
        #pragma unroll
        for (int kk = 0; kk < 64; kk += 32) {
            bf16x8 af[4], bfr[4];
            #pragma unroll
            for (int m = 0; m < 4; ++m)
                af[m] = *(const bf16x8*)&sA[(wr + m * 16 + lr) * 64 + kk + kq];
            #pragma unroll
            for (int n = 0; n < 4; ++n)
                bfr[n] = *(const bf16x8*)&sB[(wc + n * 16 + lr) * 64 + kk + kq];
            #pragma unroll
            for (int m = 0; m < 4; ++m)
                #pragma unroll
                for (int n = 0; n < 4; ++n)
                    acc[m][n] = __builtin_amdgcn_mfma_f32_16x16x32_bf16(af[m], bfr[n], acc[m][n], 0, 0, 0);
        }
    }

    const float wf = *wfac;
    const int c0 = bn * 128 + wc + lr;
    #pragma unroll
    for (int m = 0; m < 4; ++m) {
        #pragma unroll
        for (int r = 0; r < 4; ++r) {
            const int grow = bm * 128 + wr + m * 16 + (l >> 4) * 4 + r;
            const float s = rowfac[grow] * wf;
            const size_t ob = (size_t)grow * DOUT + c0;
            #pragma unroll
            for (int n = 0; n < 4; ++n)
                out[ob + n * 16] = acc[m][n][r] * s;
        }
    }
}

extern "C" void kernel_launch(void* const* d_in, const int* in_sizes, int n_in,
                              void* d_out, int out_size, void* d_ws, size_t ws_size,
                              hipStream_t stream) {
    const float* x = (const float*)d_in[0];   // [4,2048,2048]
    const float* wt = (const float*)d_in[1];  // [8192,2048]
    float* out = (float*)d_out;               // [4,2048,8192] fp32
    char* ws = (char*)d_ws;

    double* part = (double*)(ws + WS_PART);
    float* wfac = (float*)(ws + WS_WFAC);
    float* rowfac = (float*)(ws + WS_ROWFAC);
    u16* xq = (u16*)(ws + WS_XQ);
    u16* wq = (u16*)(ws + WS_WQ);

    k_wabs<<<2048, 256, 0, stream>>>(wt, part);
    k_wfin<<<1, 256, 0, stream>>>(part, wfac);
    k_wquant<<<2048, 256, 0, stream>>>(wt, wfac, wq);
    k_act<<<8192, 256, 0, stream>>>(x, xq, rowfac);
    dim3 grid(DOUT / 128, MROWS / 128);
    k_gemm<<<grid, 256, 0, stream>>>(xq, wq, rowfac, wfac, out);
}

// Round 2
// 311.758 us; speedup vs baseline: 1.4122x; 1.4122x over previous
//
#include <hip/hip_runtime.h>

typedef unsigned short u16;
typedef __bf16 bf16x8 __attribute__((ext_vector_type(8)));
typedef float f32x4 __attribute__((ext_vector_type(4)));

#define DIN 2048
#define DOUT 8192
#define MROWS 8192            // B*S = 4*2048
#define NELEM_W (8192 * 2048) // 16777216
#define NT 32                 // K-tiles of 64

// workspace layout (bytes)
#define WS_PART 0                       // double[2048] partial |w| sums
#define WS_WFAC 16384                   // float: clamped mean|w|
#define WS_ROWFAC 16640                 // float[8192]: per-row amax_c/127
#define WS_XQ 49408                     // u16[8192*2048] bf16 quantized activations
#define WS_WQ (49408 + 33554432)        // u16[8192*2048] bf16 ternary weights

// ---------------- weight abs-sum (stage 1) ----------------------------------
__global__ void k_wabs(const float* __restrict__ w, double* __restrict__ part) {
    const float4* w4 = (const float4*)w;
    const unsigned t = threadIdx.x, b = blockIdx.x;
    float s = 0.f;
    for (unsigned i = b * 256u + t; i < (NELEM_W / 4); i += 2048u * 256u) {
        float4 v = w4[i];
        s += fabsf(v.x) + fabsf(v.y) + fabsf(v.z) + fabsf(v.w);
    }
    double d = (double)s;
    #pragma unroll
    for (int o = 32; o; o >>= 1) d += __shfl_down(d, o);
    __shared__ double red[4];
    if ((t & 63u) == 0u) red[t >> 6] = d;
    __syncthreads();
    if (t == 0) part[b] = red[0] + red[1] + red[2] + red[3];
}

// ---------------- weight abs-mean (stage 2) ---------------------------------
__global__ void k_wfin(const double* __restrict__ part, float* __restrict__ wfac) {
    const int t = threadIdx.x;
    double s = 0.0;
    #pragma unroll
    for (int j = 0; j < 8; ++j) s += part[t + j * 256];
    #pragma unroll
    for (int o = 32; o; o >>= 1) s += __shfl_down(s, o);
    __shared__ double red[4];
    if ((t & 63) == 0) red[t >> 6] = s;
    __syncthreads();
    if (t == 0) {
        double mean = (red[0] + red[1] + red[2] + red[3]) * (1.0 / (double)NELEM_W);
        *wfac = fmaxf((float)mean, 1e-5f);
    }
}

// ---------------- ternary weight quant: w -> bf16 {-1,0,1} ------------------
__global__ void k_wquant(const float* __restrict__ w, const float* __restrict__ wfac,
                         u16* __restrict__ wq) {
    const float scale = 1.0f / *wfac;
    const float4* w4 = (const float4*)w;
    uint2* wo = (uint2*)wq;
    for (unsigned i = blockIdx.x * 256u + threadIdx.x; i < (NELEM_W / 4); i += 2048u * 256u) {
        float4 v = w4[i];
        unsigned q0 = __float_as_uint(fminf(fmaxf(rintf(v.x * scale), -1.f), 1.f)) >> 16;
        unsigned q1 = __float_as_uint(fminf(fmaxf(rintf(v.y * scale), -1.f), 1.f)) >> 16;
        unsigned q2 = __float_as_uint(fminf(fmaxf(rintf(v.z * scale), -1.f), 1.f)) >> 16;
        unsigned q3 = __float_as_uint(fminf(fmaxf(rintf(v.w * scale), -1.f), 1.f)) >> 16;
        uint2 u;
        u.x = q0 | (q1 << 16);
        u.y = q2 | (q3 << 16);
        wo[i] = u;
    }
}

// ---------------- fused RMS-norm + per-row int8 quant -> bf16 ints ----------
__global__ void k_act(const float* __restrict__ x, u16* __restrict__ xq,
                      float* __restrict__ rowfac) {
    const int row = blockIdx.x, t = threadIdx.x;
    const float4* xr = (const float4*)(x + (size_t)row * DIN);
    float4 v0 = xr[t], v1 = xr[t + 256];
    float ss = v0.x * v0.x + v0.y * v0.y + v0.z * v0.z + v0.w * v0.w
             + v1.x * v1.x + v1.y * v1.y + v1.z * v1.z + v1.w * v1.w;
    __shared__ float red[4];
    #pragma unroll
    for (int o = 32; o; o >>= 1) ss += __shfl_down(ss, o);
    if ((t & 63) == 0) red[t >> 6] = ss;
    __syncthreads();
    ss = red[0] + red[1] + red[2] + red[3];
    const float r = 1.0f / sqrtf(ss * (1.0f / DIN) + 1.1920929e-7f);
    float xn[8] = {v0.x * r, v0.y * r, v0.z * r, v0.w * r,
                   v1.x * r, v1.y * r, v1.z * r, v1.w * r};
    float am = 0.f;
    #pragma unroll
    for (int j = 0; j < 8; ++j) am = fmaxf(am, fabsf(xn[j]));
    __syncthreads();
    #pragma unroll
    for (int o = 32; o; o >>= 1) am = fmaxf(am, __shfl_down(am, o));
    if ((t & 63) == 0) red[t >> 6] = am;
    __syncthreads();
    am = fmaxf(fmaxf(red[0], red[1]), fmaxf(red[2], red[3]));
    const float amc = fmaxf(am, 1e-5f);
    const float s = 127.0f / amc;
    unsigned q[8];
    #pragma unroll
    for (int j = 0; j < 8; ++j) {
        float qv = fminf(fmaxf(rintf(xn[j] * s), -128.f), 127.f);
        q[j] = __float_as_uint(qv) >> 16;
    }
    uint2* xo = (uint2*)(xq + (size_t)row * DIN);
    uint2 u0, u1;
    u0.x = q[0] | (q[1] << 16); u0.y = q[2] | (q[3] << 16);
    u1.x = q[4] | (q[5] << 16); u1.y = q[6] | (q[7] << 16);
    xo[t] = u0;
    xo[t + 256] = u1;
    if (t == 0) rowfac[row] = amc * (1.0f / 127.0f);
}

// ---------------- 256x256 8-phase GEMM --------------------------------------
// C[m,n] = (sum_k Xq[m,k]*Wq[n,k]) * rowfac[m] * wfac.  Both operands [rows][K].
// 8 waves (2M x 4N), BK=64 split in two K-halves of 32; LDS [2 slot][2 kh][256][32]
// per operand, 16B-chunk XOR swizzle chunk^=((row>>1)&3). global_load_lds writes
// linearly -> inverse swizzle applied to per-lane GLOBAL source (rule #21).
// Two vmcnt(4) gates per K-tile, raw s_barrier (no implicit vmcnt drain).

// stage one 16KB half-tile (opOff: 0=A, 65536=B), 2 issues/thread
#define STAGE(gbase, opOff, tt, kh) do {                                          \
    _Pragma("unroll")                                                             \
    for (int j_ = 0; j_ < 2; ++j_) {                                              \
        const int seg_ = w * 2 + j_;                                              \
        const int row_ = seg_ * 16 + (l >> 2);                                    \
        const int sc_ = (l & 3) ^ ((l >> 3) & 3);                                 \
        const u16* src_ = (gbase) + (size_t)row_ * DIN + (tt) * 64 + (kh) * 32 + sc_ * 8; \
        __builtin_amdgcn_global_load_lds(                                         \
            (const __attribute__((address_space(1))) void*)src_,                  \
            (__attribute__((address_space(3))) void*)(smb + (opOff) + ((tt) & 1) * 32768 + (kh) * 16384 + seg_ * 1024), \
            16, 0, 0);                                                            \
    }                                                                             \
} while (0)

#define PHASE_MFMA(MBASE)                                                         \
    __builtin_amdgcn_s_barrier();                                                 \
    __builtin_amdgcn_s_setprio(1);                                                \
    _Pragma("unroll")                                                             \
    for (int i = 0; i < 4; ++i)                                                   \
        _Pragma("unroll")                                                         \
        for (int n = 0; n < 4; ++n)                                               \
            acc[(MBASE) + i][n] = __builtin_amdgcn_mfma_f32_16x16x32_bf16(        \
                afr[i], bfr[n], acc[(MBASE) + i][n], 0, 0, 0);                    \
    __builtin_amdgcn_s_setprio(0);                                                \
    __builtin_amdgcn_s_barrier();

__launch_bounds__(512, 2)
__global__ void k_gemm(const u16* __restrict__ A, const u16* __restrict__ Bw,
                       const float* __restrict__ rowfac, const float* __restrict__ wfac,
                       float* __restrict__ out) {
    __shared__ __attribute__((aligned(16))) char smb[131072]; // A[2][2][256][32], B at +65536

    const int t = threadIdx.x;
    const int l = t & 63, w = t >> 6;
    const int wm = w >> 2, wn = w & 3;
    const int lr = l & 15, lc = l >> 4;
    // swizzled per-lane fragment byte offset within a [256][32] half-buffer
    const int laneF = lr * 64 + ((lc ^ ((lr >> 1) & 3)) * 16);

    // XCD-bijective swizzle: 1024 wgs, 8 XCDs, 1024%8==0
    const int bid = blockIdx.x;
    const int wg = (bid & 7) * 128 + (bid >> 3);
    const int bm = wg >> 5, bn = wg & 31;

    const u16* Ab = A + (size_t)(bm * 256) * DIN;
    const u16* Bb = Bw + (size_t)(bn * 256) * DIN;

    f32x4 acc[8][4] = {};

    // prologue: stage tile 0 (Ak0, Bk0, Ak1, Bk1), gate first K-half
    STAGE(Ab, 0, 0, 0);
    STAGE(Bb, 65536, 0, 0);
    STAGE(Ab, 0, 0, 1);
    STAGE(Bb, 65536, 0, 1);
    asm volatile("s_waitcnt vmcnt(4)" ::: "memory");
    __builtin_amdgcn_s_barrier();

    for (int kt = 0; kt < NT; ++kt) {
        const int AB = (kt & 1) * 32768;
        const bool more = (kt < NT - 1);
        const char* aBase = smb + AB;
        const char* bBase = smb + 65536 + AB;
        bf16x8 afr[4], bfr[4];

        // ---- phase 0: kh=0, m0-3 ----
        #pragma unroll
        for (int n = 0; n < 4; ++n)
            bfr[n] = *(const bf16x8*)(bBase + (wn * 64 + n * 16) * 64 + laneF);
        #pragma unroll
        for (int i = 0; i < 4; ++i)
            afr[i] = *(const bf16x8*)(aBase + (wm * 128 + i * 16) * 64 + laneF);
        if (more) STAGE(Ab, 0, kt + 1, 0);
        PHASE_MFMA(0)

        // ---- phase 1: kh=0, m4-7 (bfr reused) ----
        #pragma unroll
        for (int i = 0; i < 4; ++i)
            afr[i] = *(const bf16x8*)(aBase + (wm * 128 + (4 + i) * 16) * 64 + laneF);
        if (more) {
            STAGE(Bb, 65536, kt + 1, 0);
            asm volatile("s_waitcnt vmcnt(4)" ::: "memory"); // tile kt's kh=1 resident
        } else {
            asm volatile("s_waitcnt vmcnt(0)" ::: "memory");
        }
        PHASE_MFMA(4)

        // ---- phase 2: kh=1, m0-3 ----
        #pragma unroll
        for (int n = 0; n < 4; ++n)
            bfr[n] = *(const bf16x8*)(bBase + 16384 + (wn * 64 + n * 16) * 64 + laneF);
        #pragma unroll
        for (int i = 0; i < 4; ++i)
            afr[i] = *(const bf16x8*)(aBase + 16384 + (wm * 128 + i * 16) * 64 + laneF);
        if (more) STAGE(Ab, 0, kt + 1, 1);
        PHASE_MFMA(0)

        // ---- phase 3: kh=1, m4-7 ----
        #pragma unroll
        for (int i = 0; i < 4; ++i)
            afr[i] = *(const bf16x8*)(aBase + 16384 + (wm * 128 + (4 + i) * 16) * 64 + laneF);
        if (more) {
            STAGE(Bb, 65536, kt + 1, 1);
            asm volatile("s_waitcnt vmcnt(4)" ::: "memory"); // tile kt+1's kh=0 resident
        }
        PHASE_MFMA(4)
    }

    // epilogue: dequant scales + fp32 store
    const float wf = *wfac;
    const int c0 = bn * 256 + wn * 64 + lr;
    #pragma unroll
    for (int m = 0; m < 8; ++m) {
        #pragma unroll
        for (int r = 0; r < 4; ++r) {
            const int grow = bm * 256 + wm * 128 + m * 16 + lc * 4 + r;
            const float s = rowfac[grow] * wf;
            const size_t ob = (size_t)grow * DOUT + c0;
            #pragma unroll
            for (int n = 0; n < 4; ++n)
                out[ob + n * 16] = acc[m][n][r] * s;
        }
    }
}

extern "C" void kernel_launch(void* const* d_in, const int* in_sizes, int n_in,
                              void* d_out, int out_size, void* d_ws, size_t ws_size,
                              hipStream_t stream) {
    const float* x = (const float*)d_in[0];   // [4,2048,2048]
    const float* wt = (const float*)d_in[1];  // [8192,2048]
    float* out = (float*)d_out;               // [4,2048,8192] fp32
    char* ws = (char*)d_ws;

    double* part = (double*)(ws + WS_PART);
    float* wfac = (float*)(ws + WS_WFAC);
    float* rowfac = (float*)(ws + WS_ROWFAC);
    u16* xq = (u16*)(ws + WS_XQ);
    u16* wq = (u16*)(ws + WS_WQ);

    k_wabs<<<2048, 256, 0, stream>>>(wt, part);
    k_wfin<<<1, 256, 0, stream>>>(part, wfac);
    k_wquant<<<2048, 256, 0, stream>>>(wt, wfac, wq);
    k_act<<<8192, 256, 0, stream>>>(x, xq, rowfac);
    k_gemm<<<1024, 512, 0, stream>>>(xq, wq, rowfac, wfac, out);
}

// Round 3
// 207.559 us; speedup vs baseline: 2.1212x; 1.5020x over previous
//
#include <hip/hip_runtime.h>

typedef unsigned short u16;
typedef unsigned int u32;
typedef int i32x4 __attribute__((ext_vector_type(4)));
typedef float f32x4 __attribute__((ext_vector_type(4)));

#define DIN 2048              // K (elements) ; int8 row = 2048 bytes
#define DOUT 8192
#define MROWS 8192            // B*S = 4*2048
#define NELEM_W (8192 * 2048) // 16777216
#define NT 16                 // K-tiles of 128 int8 (two 64B halves)

// workspace layout (bytes)
#define WS_PART 0                        // double[2048] partial |w| sums
#define WS_WFAC 16384                    // float: clamped mean|w|
#define WS_ROWFAC 16640                  // float[8192]: per-row amax_c/127
#define WS_XQ 49408                      // int8[8192*2048] quantized activations
#define WS_WQ (49408 + 16777216)         // int8[8192*2048] ternary weights

// ---------------- weight abs-sum (stage 1) ----------------------------------
__global__ void k_wabs(const float* __restrict__ w, double* __restrict__ part) {
    const float4* w4 = (const float4*)w;
    const unsigned t = threadIdx.x, b = blockIdx.x;
    float s = 0.f;
    for (unsigned i = b * 256u + t; i < (NELEM_W / 4); i += 2048u * 256u) {
        float4 v = w4[i];
        s += fabsf(v.x) + fabsf(v.y) + fabsf(v.z) + fabsf(v.w);
    }
    double d = (double)s;
    #pragma unroll
    for (int o = 32; o; o >>= 1) d += __shfl_down(d, o);
    __shared__ double red[4];
    if ((t & 63u) == 0u) red[t >> 6] = d;
    __syncthreads();
    if (t == 0) part[b] = red[0] + red[1] + red[2] + red[3];
}

// ---------------- weight abs-mean (stage 2) ---------------------------------
__global__ void k_wfin(const double* __restrict__ part, float* __restrict__ wfac) {
    const int t = threadIdx.x;
    double s = 0.0;
    #pragma unroll
    for (int j = 0; j < 8; ++j) s += part[t + j * 256];
    #pragma unroll
    for (int o = 32; o; o >>= 1) s += __shfl_down(s, o);
    __shared__ double red[4];
    if ((t & 63) == 0) red[t >> 6] = s;
    __syncthreads();
    if (t == 0) {
        double mean = (red[0] + red[1] + red[2] + red[3]) * (1.0 / (double)NELEM_W);
        *wfac = fmaxf((float)mean, 1e-5f);
    }
}

// ---------------- ternary weight quant: w -> int8 {-1,0,1} ------------------
__global__ void k_wquant(const float* __restrict__ w, const float* __restrict__ wfac,
                         u32* __restrict__ wq) {
    const float scale = 1.0f / *wfac;
    const float4* w4 = (const float4*)w;
    for (unsigned i = blockIdx.x * 256u + threadIdx.x; i < (NELEM_W / 4); i += 2048u * 256u) {
        float4 v = w4[i];
        int q0 = (int)fminf(fmaxf(rintf(v.x * scale), -1.f), 1.f);
        int q1 = (int)fminf(fmaxf(rintf(v.y * scale), -1.f), 1.f);
        int q2 = (int)fminf(fmaxf(rintf(v.z * scale), -1.f), 1.f);
        int q3 = (int)fminf(fmaxf(rintf(v.w * scale), -1.f), 1.f);
        wq[i] = (u32)(q0 & 255) | ((u32)(q1 & 255) << 8) |
                ((u32)(q2 & 255) << 16) | ((u32)(q3 & 255) << 24);
    }
}

// ---------------- fused RMS-norm + per-row int8 quant ------------------------
__global__ void k_act(const float* __restrict__ x, u32* __restrict__ xq,
                      float* __restrict__ rowfac) {
    const int row = blockIdx.x, t = threadIdx.x;
    const float4* xr = (const float4*)(x + (size_t)row * DIN);
    float4 v0 = xr[t], v1 = xr[t + 256];
    float ss = v0.x * v0.x + v0.y * v0.y + v0.z * v0.z + v0.w * v0.w
             + v1.x * v1.x + v1.y * v1.y + v1.z * v1.z + v1.w * v1.w;
    __shared__ float red[4];
    #pragma unroll
    for (int o = 32; o; o >>= 1) ss += __shfl_down(ss, o);
    if ((t & 63) == 0) red[t >> 6] = ss;
    __syncthreads();
    ss = red[0] + red[1] + red[2] + red[3];
    const float r = 1.0f / sqrtf(ss * (1.0f / DIN) + 1.1920929e-7f);
    float xn[8] = {v0.x * r, v0.y * r, v0.z * r, v0.w * r,
                   v1.x * r, v1.y * r, v1.z * r, v1.w * r};
    float am = 0.f;
    #pragma unroll
    for (int j = 0; j < 8; ++j) am = fmaxf(am, fabsf(xn[j]));
    __syncthreads();
    #pragma unroll
    for (int o = 32; o; o >>= 1) am = fmaxf(am, __shfl_down(am, o));
    if ((t & 63) == 0) red[t >> 6] = am;
    __syncthreads();
    am = fmaxf(fmaxf(red[0], red[1]), fmaxf(red[2], red[3]));
    const float amc = fmaxf(am, 1e-5f);
    const float s = 127.0f / amc;
    int q[8];
    #pragma unroll
    for (int j = 0; j < 8; ++j)
        q[j] = (int)fminf(fmaxf(rintf(xn[j] * s), -128.f), 127.f);
    u32* xo = xq + (size_t)row * (DIN / 4);
    xo[t] = (u32)(q[0] & 255) | ((u32)(q[1] & 255) << 8) |
            ((u32)(q[2] & 255) << 16) | ((u32)(q[3] & 255) << 24);
    xo[t + 256] = (u32)(q[4] & 255) | ((u32)(q[5] & 255) << 8) |
                  ((u32)(q[6] & 255) << 16) | ((u32)(q[7] & 255) << 24);
    if (t == 0) rowfac[row] = amc * (1.0f / 127.0f);
}

// ---------------- 256x256 8-phase int8 GEMM ----------------------------------
// C[m,n] = (sum_k Xq[m,k]*Wq[n,k]) * rowfac[m] * wfac.  Operands int8 [rows][K].
// Byte-identical tile geometry to the verified bf16 kernel: LDS half-buffers
// [256 rows][64 B] (now K-half = 64 int8), 16B-granule XOR swizzle
// granule ^= ((row>>1)&3) applied to the per-lane GLOBAL source (rule #21).
// K-tile = 128 int8 -> NT=16. mfma_i32_16x16x64_i8: lane row = l&15,
// k-bytes = (l>>4)*16 .. +15 — identical byte addressing to the bf16 frag.
// Two vmcnt(4) gates per K-tile, raw s_barrier.

#define STAGE(gbase, opOff, tt, kh) do {                                          \
    _Pragma("unroll")                                                             \
    for (int j_ = 0; j_ < 2; ++j_) {                                              \
        const int seg_ = w * 2 + j_;                                              \
        const int row_ = seg_ * 16 + (l >> 2);                                    \
        const int sc_ = (l & 3) ^ ((l >> 3) & 3);                                 \
        const char* src_ = (gbase) + (size_t)row_ * DIN + (tt) * 128 + (kh) * 64 + sc_ * 16; \
        __builtin_amdgcn_global_load_lds(                                         \
            (const __attribute__((address_space(1))) void*)src_,                  \
            (__attribute__((address_space(3))) void*)(smb + (opOff) + ((tt) & 1) * 32768 + (kh) * 16384 + seg_ * 1024), \
            16, 0, 0);                                                            \
    }                                                                             \
} while (0)

#define PHASE_MFMA(MBASE)                                                         \
    __builtin_amdgcn_s_barrier();                                                 \
    __builtin_amdgcn_s_setprio(1);                                                \
    _Pragma("unroll")                                                             \
    for (int i = 0; i < 4; ++i)                                                   \
        _Pragma("unroll")                                                         \
        for (int n = 0; n < 4; ++n)                                               \
            acc[(MBASE) + i][n] = __builtin_amdgcn_mfma_i32_16x16x64_i8(          \
                afr[i], bfr[n], acc[(MBASE) + i][n], 0, 0, 0);                    \
    __builtin_amdgcn_s_setprio(0);                                                \
    __builtin_amdgcn_s_barrier();

__launch_bounds__(512, 2)
__global__ void k_gemm(const char* __restrict__ A, const char* __restrict__ Bw,
                       const float* __restrict__ rowfac, const float* __restrict__ wfac,
                       float* __restrict__ out) {
    __shared__ __attribute__((aligned(16))) char smb[131072]; // A[2][2][256][64B], B at +65536

    const int t = threadIdx.x;
    const int l = t & 63, w = t >> 6;
    const int wm = w >> 2, wn = w & 3;
    const int lr = l & 15, lc = l >> 4;
    // swizzled per-lane fragment byte offset within a [256][64B] half-buffer
    const int laneF = lr * 64 + ((lc ^ ((lr >> 1) & 3)) * 16);

    // XCD-bijective swizzle: 1024 wgs % 8 == 0
    const int bid = blockIdx.x;
    const int wg = (bid & 7) * 128 + (bid >> 3);
    const int bm = wg >> 5, bn = wg & 31;

    const char* Ab = A + (size_t)(bm * 256) * DIN;
    const char* Bb = Bw + (size_t)(bn * 256) * DIN;

    i32x4 acc[8][4] = {};

    // prologue: stage tile 0, gate first K-half
    STAGE(Ab, 0, 0, 0);
    STAGE(Bb, 65536, 0, 0);
    STAGE(Ab, 0, 0, 1);
    STAGE(Bb, 65536, 0, 1);
    asm volatile("s_waitcnt vmcnt(4)" ::: "memory");
    __builtin_amdgcn_s_barrier();

    for (int kt = 0; kt < NT; ++kt) {
        const int AB = (kt & 1) * 32768;
        const bool more = (kt < NT - 1);
        const char* aBase = smb + AB;
        const char* bBase = smb + 65536 + AB;
        i32x4 afr[4], bfr[4];

        // ---- phase 0: kh=0, m0-3 ----
        #pragma unroll
        for (int n = 0; n < 4; ++n)
            bfr[n] = *(const i32x4*)(bBase + (wn * 64 + n * 16) * 64 + laneF);
        #pragma unroll
        for (int i = 0; i < 4; ++i)
            afr[i] = *(const i32x4*)(aBase + (wm * 128 + i * 16) * 64 + laneF);
        if (more) STAGE(Ab, 0, kt + 1, 0);
        PHASE_MFMA(0)

        // ---- phase 1: kh=0, m4-7 (bfr reused) ----
        #pragma unroll
        for (int i = 0; i < 4; ++i)
            afr[i] = *(const i32x4*)(aBase + (wm * 128 + (4 + i) * 16) * 64 + laneF);
        if (more) {
            STAGE(Bb, 65536, kt + 1, 0);
            asm volatile("s_waitcnt vmcnt(4)" ::: "memory"); // tile kt's kh=1 resident
        } else {
            asm volatile("s_waitcnt vmcnt(0)" ::: "memory");
        }
        PHASE_MFMA(4)

        // ---- phase 2: kh=1, m0-3 ----
        #pragma unroll
        for (int n = 0; n < 4; ++n)
            bfr[n] = *(const i32x4*)(bBase + 16384 + (wn * 64 + n * 16) * 64 + laneF);
        #pragma unroll
        for (int i = 0; i < 4; ++i)
            afr[i] = *(const i32x4*)(aBase + 16384 + (wm * 128 + i * 16) * 64 + laneF);
        if (more) STAGE(Ab, 0, kt + 1, 1);
        PHASE_MFMA(0)

        // ---- phase 3: kh=1, m4-7 ----
        #pragma unroll
        for (int i = 0; i < 4; ++i)
            afr[i] = *(const i32x4*)(aBase + 16384 + (wm * 128 + (4 + i) * 16) * 64 + laneF);
        if (more) {
            STAGE(Bb, 65536, kt + 1, 1);
            asm volatile("s_waitcnt vmcnt(4)" ::: "memory"); // tile kt+1's kh=0 resident
        }
        PHASE_MFMA(4)
    }

    // epilogue: exact int32 -> fp32, dequant scales, store
    const float wf = *wfac;
    const int c0 = bn * 256 + wn * 64 + lr;
    #pragma unroll
    for (int m = 0; m < 8; ++m) {
        #pragma unroll
        for (int r = 0; r < 4; ++r) {
            const int grow = bm * 256 + wm * 128 + m * 16 + lc * 4 + r;
            const float s = rowfac[grow] * wf;
            const size_t ob = (size_t)grow * DOUT + c0;
            #pragma unroll
            for (int n = 0; n < 4; ++n)
                out[ob + n * 16] = (float)acc[m][n][r] * s;
        }
    }
}

extern "C" void kernel_launch(void* const* d_in, const int* in_sizes, int n_in,
                              void* d_out, int out_size, void* d_ws, size_t ws_size,
                              hipStream_t stream) {
    const float* x = (const float*)d_in[0];   // [4,2048,2048]
    const float* wt = (const float*)d_in[1];  // [8192,2048]
    float* out = (float*)d_out;               // [4,2048,8192] fp32
    char* ws = (char*)d_ws;

    double* part = (double*)(ws + WS_PART);
    float* wfac = (float*)(ws + WS_WFAC);
    float* rowfac = (float*)(ws + WS_ROWFAC);
    u32* xq = (u32*)(ws + WS_XQ);
    u32* wq = (u32*)(ws + WS_WQ);

    k_wabs<<<2048, 256, 0, stream>>>(wt, part);
    k_wfin<<<1, 256, 0, stream>>>(part, wfac);
    k_wquant<<<2048, 256, 0, stream>>>(wt, wfac, wq);
    k_act<<<8192, 256, 0, stream>>>(x, xq, rowfac);
    k_gemm<<<1024, 512, 0, stream>>>((const char*)xq, (const char*)wq, rowfac, wfac, out);
}

// Round 4
// 203.750 us; speedup vs baseline: 2.1608x; 1.0187x over previous
//
#include <hip/hip_runtime.h>

typedef unsigned short u16;
typedef unsigned int u32;
typedef int i32x4 __attribute__((ext_vector_type(4)));

#define DIN 2048              // K elements; int8 row = 2048 bytes
#define DOUT 8192
#define MROWS 8192            // B*S
#define NELEM_W (8192 * 2048)

// workspace layout (bytes)
#define WS_PART 0                        // double[2048]
#define WS_WFAC 16384                    // float
#define WS_ROWFAC 16640                  // float[8192]
#define WS_XQ 49408                      // int8[8192*2048]
#define WS_WQ (49408 + 16777216)         // int8[8192*2048]

// ---------------- weight abs-sum (stage 1) ----------------------------------
__global__ void k_wabs(const float* __restrict__ w, double* __restrict__ part) {
    const float4* w4 = (const float4*)w;
    const unsigned t = threadIdx.x, b = blockIdx.x;
    float s = 0.f;
    for (unsigned i = b * 256u + t; i < (NELEM_W / 4); i += 2048u * 256u) {
        float4 v = w4[i];
        s += fabsf(v.x) + fabsf(v.y) + fabsf(v.z) + fabsf(v.w);
    }
    double d = (double)s;
    #pragma unroll
    for (int o = 32; o; o >>= 1) d += __shfl_down(d, o);
    __shared__ double red[4];
    if ((t & 63u) == 0u) red[t >> 6] = d;
    __syncthreads();
    if (t == 0) part[b] = red[0] + red[1] + red[2] + red[3];
}

// ---------------- weight abs-mean (stage 2) ---------------------------------
__global__ void k_wfin(const double* __restrict__ part, float* __restrict__ wfac) {
    const int t = threadIdx.x;
    double s = 0.0;
    #pragma unroll
    for (int j = 0; j < 8; ++j) s += part[t + j * 256];
    #pragma unroll
    for (int o = 32; o; o >>= 1) s += __shfl_down(s, o);
    __shared__ double red[4];
    if ((t & 63) == 0) red[t >> 6] = s;
    __syncthreads();
    if (t == 0) {
        double mean = (red[0] + red[1] + red[2] + red[3]) * (1.0 / (double)NELEM_W);
        *wfac = fmaxf((float)mean, 1e-5f);
    }
}

// ---------------- fused: ternary weight quant + RMS-norm/act quant ----------
__global__ void k_prep(const float* __restrict__ w, const float* __restrict__ wfac,
                       u32* __restrict__ wq, const float* __restrict__ x,
                       u32* __restrict__ xq, float* __restrict__ rowfac) {
    const int t = threadIdx.x;
    if (blockIdx.x < 2048) {
        // ---- weight quant part ----
        const float scale = 1.0f / *wfac;
        const float4* w4 = (const float4*)w;
        for (unsigned i = blockIdx.x * 256u + t; i < (NELEM_W / 4); i += 2048u * 256u) {
            float4 v = w4[i];
            int q0 = (int)fminf(fmaxf(rintf(v.x * scale), -1.f), 1.f);
            int q1 = (int)fminf(fmaxf(rintf(v.y * scale), -1.f), 1.f);
            int q2 = (int)fminf(fmaxf(rintf(v.z * scale), -1.f), 1.f);
            int q3 = (int)fminf(fmaxf(rintf(v.w * scale), -1.f), 1.f);
            wq[i] = (u32)(q0 & 255) | ((u32)(q1 & 255) << 8) |
                    ((u32)(q2 & 255) << 16) | ((u32)(q3 & 255) << 24);
        }
        return;
    }
    // ---- activation part: one row per block ----
    const int row = blockIdx.x - 2048;
    const float4* xr = (const float4*)(x + (size_t)row * DIN);
    float4 v0 = xr[t], v1 = xr[t + 256];
    float ss = v0.x * v0.x + v0.y * v0.y + v0.z * v0.z + v0.w * v0.w
             + v1.x * v1.x + v1.y * v1.y + v1.z * v1.z + v1.w * v1.w;
    __shared__ float red[4];
    #pragma unroll
    for (int o = 32; o; o >>= 1) ss += __shfl_down(ss, o);
    if ((t & 63) == 0) red[t >> 6] = ss;
    __syncthreads();
    ss = red[0] + red[1] + red[2] + red[3];
    const float r = 1.0f / sqrtf(ss * (1.0f / DIN) + 1.1920929e-7f);
    float xn[8] = {v0.x * r, v0.y * r, v0.z * r, v0.w * r,
                   v1.x * r, v1.y * r, v1.z * r, v1.w * r};
    float am = 0.f;
    #pragma unroll
    for (int j = 0; j < 8; ++j) am = fmaxf(am, fabsf(xn[j]));
    __syncthreads();
    #pragma unroll
    for (int o = 32; o; o >>= 1) am = fmaxf(am, __shfl_down(am, o));
    if ((t & 63) == 0) red[t >> 6] = am;
    __syncthreads();
    am = fmaxf(fmaxf(red[0], red[1]), fmaxf(red[2], red[3]));
    const float amc = fmaxf(am, 1e-5f);
    const float s = 127.0f / amc;
    int q[8];
    #pragma unroll
    for (int j = 0; j < 8; ++j)
        q[j] = (int)fminf(fmaxf(rintf(xn[j] * s), -128.f), 127.f);
    u32* xo = xq + (size_t)row * (DIN / 4);
    xo[t] = (u32)(q[0] & 255) | ((u32)(q[1] & 255) << 8) |
            ((u32)(q[2] & 255) << 16) | ((u32)(q[3] & 255) << 24);
    xo[t + 256] = (u32)(q[4] & 255) | ((u32)(q[5] & 255) << 8) |
                  ((u32)(q[6] & 255) << 16) | ((u32)(q[7] & 255) << 24);
    if (t == 0) rowfac[row] = amc * (1.0f / 127.0f);
}

// ---------------- 256x256 int8 GEMM: full-tile reg preload, 1 barrier/tile ---
// LDS map: A slots @ 0 / 32768 ; B slots @ 65536 / 98304. Row = 128B (full
// K-tile), 16B granule swizzle g ^= (row&7), inverse applied to global src.
// Per K-tile: STAGE(kt+1, other slot) -> 64 MFMA on preloaded frags(kt)
// -> vmcnt(0) (free; loads flew under MFMA) -> s_barrier -> issue 24 ds_read
// for frags(kt+1) with NO wait (drain under next tile's MFMA via counted lgkm).
__launch_bounds__(512, 2)
__global__ void k_gemm(const char* __restrict__ A, const char* __restrict__ Bw,
                       const float* __restrict__ rowfac, const float* __restrict__ wfac,
                       float* __restrict__ out) {
    __shared__ __attribute__((aligned(16))) char smb[131072];

    const int t = threadIdx.x;
    const int l = t & 63, w = t >> 6;
    const int wm = w >> 2, wn = w & 3;
    const int lr = l & 15, lc = l >> 4;
    const int swzr = lr & 7;
    // read bases (byte offsets in smb); kh1 granule = (4+lc)^swzr
    const int aB0 = (wm * 128 + lr) * 128 + ((lc ^ swzr) * 16);
    const int aB1 = (wm * 128 + lr) * 128 + (((4 + lc) ^ swzr) * 16);
    const int bB0 = 65536 + (wn * 64 + lr) * 128 + ((lc ^ swzr) * 16);
    const int bB1 = 65536 + (wn * 64 + lr) * 128 + (((4 + lc) ^ swzr) * 16);

    // XCD-bijective block swizzle (1024 % 8 == 0)
    const int bid = blockIdx.x;
    const int wg = (bid & 7) * 128 + (bid >> 3);
    const int bm = wg >> 5, bn = wg & 31;
    const char* Ab = A + (size_t)(bm * 256) * DIN;
    const char* Bb = Bw + (size_t)(bn * 256) * DIN;

    // stage addressing: thread t, issue j writes LDS linear j*8192 + t*16
    // = phys (row = j*64 + t>>3, g = t&7); source logical g = (t&7)^(row&7)
    const int srow = t >> 3;
    const int loff = srow * DIN + (((t & 7) ^ (srow & 7)) * 16);
    const int ldst = t * 16;

    i32x4 acc[8][4] = {};
    i32x4 fa[2][8], fb[2][4];

#define STG(ktB, s) do {                                                          \
    _Pragma("unroll")                                                             \
    for (int j_ = 0; j_ < 4; ++j_)                                                \
        __builtin_amdgcn_global_load_lds(                                         \
            (const __attribute__((address_space(1))) void*)(Ab + (size_t)(j_ * 64) * DIN + loff + (ktB)), \
            (__attribute__((address_space(3))) void*)(smb + (s) * 32768 + j_ * 8192 + ldst), 16, 0, 0); \
    _Pragma("unroll")                                                             \
    for (int j_ = 0; j_ < 4; ++j_)                                                \
        __builtin_amdgcn_global_load_lds(                                         \
            (const __attribute__((address_space(1))) void*)(Bb + (size_t)(j_ * 64) * DIN + loff + (ktB)), \
            (__attribute__((address_space(3))) void*)(smb + 65536 + (s) * 32768 + j_ * 8192 + ldst), 16, 0, 0); \
} while (0)

#define RDA(s) do {                                                               \
    _Pragma("unroll")                                                             \
    for (int m_ = 0; m_ < 8; ++m_) {                                              \
        fa[0][m_] = *(const i32x4*)(smb + (s) * 32768 + aB0 + m_ * 2048);         \
        fa[1][m_] = *(const i32x4*)(smb + (s) * 32768 + aB1 + m_ * 2048);         \
    }                                                                             \
    _Pragma("unroll")                                                             \
    for (int n_ = 0; n_ < 4; ++n_) {                                              \
        fb[0][n_] = *(const i32x4*)(smb + (s) * 32768 + bB0 + n_ * 2048);         \
        fb[1][n_] = *(const i32x4*)(smb + (s) * 32768 + bB1 + n_ * 2048);         \
    }                                                                             \
} while (0)

#define MFM() do {                                                                \
    __builtin_amdgcn_s_setprio(1);                                                \
    _Pragma("unroll")                                                             \
    for (int kh_ = 0; kh_ < 2; ++kh_)                                             \
        _Pragma("unroll")                                                         \
        for (int m_ = 0; m_ < 8; ++m_)                                            \
            _Pragma("unroll")                                                     \
            for (int n_ = 0; n_ < 4; ++n_)                                        \
                acc[m_][n_] = __builtin_amdgcn_mfma_i32_16x16x64_i8(              \
                    fa[kh_][m_], fb[kh_][n_], acc[m_][n_], 0, 0, 0);              \
    __builtin_amdgcn_s_setprio(0);                                                \
} while (0)

#define GATE() do {                                                               \
    asm volatile("s_waitcnt vmcnt(0)" ::: "memory");                              \
    __builtin_amdgcn_s_barrier();                                                 \
} while (0)

    // prologue: tile 0 into slot 0
    STG(0, 0);
    GATE();
    RDA(0);

    int kb = 128;
    #pragma unroll 1
    for (int pair = 0; pair < 7; ++pair) {
        STG(kb, 1);          // tile kt+1 -> slot 1
        MFM();               // tile kt (slot-0 frags)
        GATE();
        RDA(1);
        STG(kb + 128, 0);    // tile kt+2 -> slot 0
        MFM();               // tile kt+1
        GATE();
        RDA(0);
        kb += 256;
    }
    // kt=14: stage tile 15, compute 14
    STG(kb, 1);
    MFM();
    GATE();
    RDA(1);
    MFM();                   // kt=15

    // epilogue: exact int32 -> fp32, dequant scales, store
    const float wf = *wfac;
    const int c0 = bn * 256 + wn * 64 + lr;
    #pragma unroll
    for (int m = 0; m < 8; ++m) {
        #pragma unroll
        for (int r = 0; r < 4; ++r) {
            const int grow = bm * 256 + wm * 128 + m * 16 + lc * 4 + r;
            const float s = rowfac[grow] * wf;
            const size_t ob = (size_t)grow * DOUT + c0;
            #pragma unroll
            for (int n = 0; n < 4; ++n)
                out[ob + n * 16] = (float)acc[m][n][r] * s;
        }
    }
#undef STG
#undef RDA
#undef MFM
#undef GATE
}

extern "C" void kernel_launch(void* const* d_in, const int* in_sizes, int n_in,
                              void* d_out, int out_size, void* d_ws, size_t ws_size,
                              hipStream_t stream) {
    const float* x = (const float*)d_in[0];   // [4,2048,2048]
    const float* wt = (const float*)d_in[1];  // [8192,2048]
    float* out = (float*)d_out;               // [4,2048,8192] fp32
    char* ws = (char*)d_ws;

    double* part = (double*)(ws + WS_PART);
    float* wfac = (float*)(ws + WS_WFAC);
    float* rowfac = (float*)(ws + WS_ROWFAC);
    u32* xq = (u32*)(ws + WS_XQ);
    u32* wq = (u32*)(ws + WS_WQ);

    k_wabs<<<2048, 256, 0, stream>>>(wt, part);
    k_wfin<<<1, 256, 0, stream>>>(part, wfac);
    k_prep<<<2048 + MROWS, 256, 0, stream>>>(wt, wfac, wq, x, xq, rowfac);
    k_gemm<<<1024, 512, 0, stream>>>((const char*)xq, (const char*)wq, rowfac, wfac, out);
}